// Round 1
// baseline (2265.341 us; speedup 1.0000x reference)
//
#include <hip/hip_runtime.h>
#include <math.h>

// Problem constants (match reference)
#define NSAMP 220500
#define NCH   28
#define L_GT  1000
#define L_ENV 2000
#define L4    3997   // 4x cascaded gammatone -> combined FIR length 4*999+1
#define HPCH  24     // channels 4..27 get HP
#define TILE  2048
#define BLOCK 256
#define RPT   8

// LDS swizzle: stride-8 register-window reads become stride-9 -> conflict-free
__device__ __forceinline__ int swz(int i) { return i + (i >> 3); }

// ---------------------------------------------------------------------------
// Generic tiled causal FIR. One block = one (channel, 2048-output tile).
// Each thread: 8 consecutive outputs, sliding x-window in registers,
// 1 LDS read + 8 FMA per tap; taps via uniform (scalar) loads.
// DELAYED: input fetched as pass_del[p] = (p+d<N) ? in[p+d] : 0  (exact ref
// semantics of delay-then-FIR, including the partial-sum tail).
// ---------------------------------------------------------------------------
template<int L, bool ABSIN, bool DELAYED>
__global__ __launch_bounds__(BLOCK)
void fir_big(const float* __restrict__ in, int instride,
             const float* __restrict__ taps, int tapstride,
             float* __restrict__ out, int ostride,
             const int* __restrict__ delays, int chan0)
{
    extern __shared__ float s[];
    const int c  = blockIdx.y;
    const int n0 = blockIdx.x * TILE;
    const float* __restrict__ xin = in  + (long)c * instride;
    const float* __restrict__ h   = taps + (long)c * tapstride;
    float* __restrict__ y         = out + (long)c * ostride;
    int d = 0;
    if (DELAYED) d = delays[chan0 + c];

    const int E = TILE + L - 1;       // staged extent (logical 0 .. E-1)
    const int PADLO = 8;              // dead low slots for final window loads
    for (int i = threadIdx.x; i < E; i += BLOCK) {
        int p = n0 - (L - 1) + i;     // logical sample index
        float v = 0.f;
        if (p >= 0 && p < NSAMP) {
            int q = p + d;            // q==p when !DELAYED (d=0)
            if (!DELAYED || q < NSAMP) v = xin[q];
        }
        if (ABSIN) v = fabsf(v);
        s[swz(i + PADLO)] = v;
    }
    __syncthreads();

    const int t  = threadIdx.x;
    const int bi = (L - 1) + t * RPT + PADLO;  // swizzle-space logical base
    float acc[RPT];
    float w[RPT];
#pragma unroll
    for (int j = 0; j < RPT; j++) { acc[j] = 0.f; w[j] = s[swz(bi + j)]; }

#pragma unroll 8
    for (int k = 0; k < L; k++) {
        float hk = h[k];              // uniform -> s_load
#pragma unroll
        for (int j = 0; j < RPT; j++) acc[j] = fmaf(hk, w[j], acc[j]);
#pragma unroll
        for (int j = RPT - 1; j > 0; j--) w[j] = w[j - 1];
        w[0] = s[swz(bi - 1 - k)];    // one new value per tap (dead on last iter)
    }

#pragma unroll
    for (int j = 0; j < RPT; j++) {
        int n = n0 + t * RPT + j;
        if (n < NSAMP) y[n] = acc[j];
    }
}

// ---------------------------------------------------------------------------
// Backward (anti-causal) envelope FIR fused with loudness recruitment.
// env[c,n] = sum_k h[c,k] * |env_f[c,n+k]|  (zero past N-1)
// then gain; coch_c overwrites pass_del in place (1:1 element ownership).
// ---------------------------------------------------------------------------
template<int L>
__global__ __launch_bounds__(BLOCK)
void env_gain(const float* __restrict__ envf,
              const float* __restrict__ taps, int tapstride,
              float* __restrict__ pc,           // in: pass_del, out: coch_c
              const float* __restrict__ ratios,
              const float* __restrict__ eqloud)
{
    extern __shared__ float s[];
    const int c  = blockIdx.y;
    const int n0 = blockIdx.x * TILE;
    const float* __restrict__ xin = envf + (long)c * NSAMP;
    const float* __restrict__ h   = taps + (long)c * tapstride;

    const int E = TILE + L - 1;
    for (int i = threadIdx.x; i < E; i += BLOCK) {
        int p = n0 + i;
        float v = (p < NSAMP) ? fabsf(xin[p]) : 0.f;   // zero-fill implements n+k<N cut
        s[swz(i)] = v;
    }
    __syncthreads();

    const int t  = threadIdx.x;
    const int bi = t * RPT;
    float acc[RPT];
    float w[RPT];
#pragma unroll
    for (int j = 0; j < RPT; j++) { acc[j] = 0.f; w[j] = s[swz(bi + j)]; }

#pragma unroll 8
    for (int k = 0; k < L; k++) {
        float hk = h[k];
#pragma unroll
        for (int j = 0; j < RPT; j++) acc[j] = fmaf(hk, w[j], acc[j]);
#pragma unroll
        for (int j = 0; j < RPT - 1; j++) w[j] = w[j + 1];
        w[RPT - 1] = s[swz(bi + RPT + k)];  // dead read on last iter (PADHI)
    }

    const float emax = exp10f(0.05f * (eqloud[c] - 100.0f));
    const float er   = fmaxf(ratios[c], -5.0f) - 1.0f;
#pragma unroll
    for (int j = 0; j < RPT; j++) {
        int n = n0 + t * RPT + j;
        if (n < NSAMP) {
            float env = acc[j];
            float ecl = fminf(fmaxf(env, 1e-9f), emax);
            float enr = fmaxf(ecl / emax, 1e-6f);
            float g   = fminf(powf(enr, er), 100.0f);
            long idx = (long)c * NSAMP + n;
            pc[idx] = pc[idx] * g;
        }
    }
}

// out[c,m] = sum_k a[c,k] * a[c,m-k]   (self convolution, m < 2*La-1)
__global__ void conv_self(const float* __restrict__ a, int astride, int La,
                          float* __restrict__ out, int ostride, int Mlen)
{
    extern __shared__ float s[];
    const int c = blockIdx.y;
    const float* __restrict__ ar = a + (long)c * astride;
    for (int i = threadIdx.x; i < La; i += blockDim.x) s[i] = ar[i];
    __syncthreads();
    int m = blockIdx.x * blockDim.x + threadIdx.x;
    float acc = 0.f;
    for (int k = 0; k < La; k++) {
        int mi = m - k;
        float bv = ((unsigned)mi < (unsigned)La) ? s[mi] : 0.f;
        acc = fmaf(s[k], bv, acc);
    }
    if (m < Mlen) out[(long)c * ostride + m] = acc;
}

// pass_del for channels without HP: b[c,n] = (n+d<N) ? a[c,n+d] : 0
__global__ void delay_copy(const float* __restrict__ a, float* __restrict__ b,
                           const int* __restrict__ delays)
{
    int c = blockIdx.y;
    int n = blockIdx.x * blockDim.x + threadIdx.x;
    if (n < NSAMP) {
        int q = n + delays[c];
        b[(long)c * NSAMP + n] = (q < NSAMP) ? a[(long)c * NSAMP + q] : 0.f;
    }
}

// coch[n] = 10^-0.5 * sum_c coch_c[c,n]
__global__ void reduce_coch(const float* __restrict__ b, float* __restrict__ coch)
{
    int n = blockIdx.x * blockDim.x + threadIdx.x;
    if (n < NSAMP) {
        float sum = 0.f;
        for (int c = 0; c < NCH; c++) sum += b[(long)c * NSAMP + n];
        coch[n] = sum * 0.31622776601683794f;  // 10^(-0.05*10)
    }
}

static inline size_t lds_fir_bytes(int L)
{
    int top = 8 /*PADLO*/ + (TILE + L - 1) + 8 /*PADHI*/;
    return (size_t)(top + (top >> 3) + 2) * 4;
}

extern "C" void kernel_launch(void* const* d_in, const int* in_sizes, int n_in,
                              void* d_out, int out_size, void* d_ws, size_t ws_size,
                              hipStream_t stream)
{
    const float* x       = (const float*)d_in[0];
    const float* src_fwd = (const float*)d_in[1];
    const float* src_bwd = (const float*)d_in[2];
    const float* lpf     = (const float*)d_in[3];
    const float* gtn     = (const float*)d_in[4];  // [28,1000]
    const float* hp      = (const float*)d_in[5];  // [24,1000]
    const float* clpf    = (const float*)d_in[6];  // [28,2000]
    const float* ratios  = (const float*)d_in[7];
    const float* eqloud  = (const float*)d_in[8];
    const int*   delays  = (const int*)d_in[9];
    float* out = (float*)d_out;

    // Workspace layout (floats): 2 big C*N buffers + 3 N buffers + composed taps
    float* ws   = (float*)d_ws;
    const size_t CNs = (size_t)NCH * NSAMP;
    float* bufA = ws;                    // C*N   (y4, then env_f)
    float* bufB = bufA + CNs;            // C*N   (pass_del, then coch_c in place)
    float* xc   = bufB + CNs;            // N
    float* coch = xc + NSAMP;            // N
    float* t1   = coch + NSAMP;          // N
    float* h2   = t1 + NSAMP;            // 28*2000
    float* h4   = h2 + (size_t)NCH * 2000;  // 28*4000

    dim3 blk(BLOCK);
    const int NT = (NSAMP + TILE - 1) / TILE;  // 108

    // Compose gammatone^4: h2 = h*h (len 1999), h4 = h2*h2 (len 3997)
    conv_self<<<dim3((2 * L_GT - 1 + BLOCK - 1) / BLOCK, NCH), blk, L_GT * 4, stream>>>(
        gtn, L_GT, L_GT, h2, 2000, 2 * L_GT - 1);
    conv_self<<<dim3((L4 + BLOCK - 1) / BLOCK, NCH), blk, 1999 * 4, stream>>>(
        h2, 2000, 1999, h4, 4000, L4);

    // xc = fir1(x, src_fwd)
    fir_big<256, false, false><<<dim3(NT, 1), blk, lds_fir_bytes(256), stream>>>(
        x, 0, src_fwd, 0, xc, 0, nullptr, 0);

    // y4[c] = xc * h4[c]  (shared input broadcast; the 4-pass cascade collapsed)
    fir_big<L4, false, false><<<dim3(NT, NCH), blk, lds_fir_bytes(L4), stream>>>(
        xc, 0, h4, 4000, bufA, NSAMP, nullptr, 0);

    // pass_del channels 0..3: plain delayed copy
    delay_copy<<<dim3((NSAMP + BLOCK - 1) / BLOCK, 4), blk, 0, stream>>>(bufA, bufB, delays);

    // pass_del channels 4..27: HP FIR with delay applied at input fetch
    fir_big<L_GT, false, true><<<dim3(NT, HPCH), blk, lds_fir_bytes(L_GT), stream>>>(
        bufA + 4 * (size_t)NSAMP, NSAMP, hp, L_GT,
        bufB + 4 * (size_t)NSAMP, NSAMP, delays, 4);

    // env_f = fir(|pass_del|, chan_lpf)
    fir_big<L_ENV, true, false><<<dim3(NT, NCH), blk, lds_fir_bytes(L_ENV), stream>>>(
        bufB, NSAMP, clpf, 2000, bufA, NSAMP, nullptr, 0);

    // env (anti-causal) + recruitment gain; coch_c overwrites pass_del in bufB
    {
        int top = (TILE + L_ENV - 1) + 8;
        size_t lds = (size_t)(top + (top >> 3) + 2) * 4;
        env_gain<L_ENV><<<dim3(NT, NCH), blk, lds, stream>>>(
            bufA, clpf, 2000, bufB, ratios, eqloud);
    }

    // coch = 10^-0.5 * sum_c coch_c
    reduce_coch<<<dim3((NSAMP + BLOCK - 1) / BLOCK), blk, 0, stream>>>(bufB, coch);

    // out = fir1(fir1(coch, src_bwd), lpf)
    fir_big<256, false, false><<<dim3(NT, 1), blk, lds_fir_bytes(256), stream>>>(
        coch, 0, src_bwd, 0, t1, 0, nullptr, 0);
    fir_big<133, false, false><<<dim3(NT, 1), blk, lds_fir_bytes(133), stream>>>(
        t1, 0, lpf, 0, out, 0, nullptr, 0);
}

// Round 3
// 1799.766 us; speedup vs baseline: 1.2587x; 1.2587x over previous
//
#include <hip/hip_runtime.h>
#include <math.h>

// Problem constants (match reference)
#define NSAMP 220500
#define NCH   28
#define L_GT  1000
#define L_ENV 2000
#define L4    3997   // 4x cascaded gammatone -> combined FIR length
#define HPCH  24     // channels 4..27 get HP
#define TILE  2048
#define BLOCK 256

// Padded tap lengths (multiples of 24 -> tapcount/8 divisible by 3, no tail)
#define LP_GT4 4008
#define LP_HP  1008
#define LP_ENV 2016
#define LP_SRC 264
#define LP_LPF 144

typedef __attribute__((ext_vector_type(4))) float f32x4;

// Padded-LDS layout: logical float index u -> physical u + 4*(u>>3)
// (4-float pad after every 8 floats). Logical 8-block b maps to physical
// [12b, 12b+8); pad at [12b+8, 12b+12). Per-thread b128 stride = 12 floats
// = 48B -> lanes 0..7 cover all 32 banks once -> conflict-free b128.
__device__ __forceinline__ int physu(int u) { return u + ((u >> 3) << 2); }

template<int I>
__device__ __forceinline__ float wselT(const f32x4& a, const f32x4& b,
                                       const f32x4& c, const f32x4& d)
{
    if constexpr (I < 4)       return a[I];
    else if constexpr (I < 8)  return b[I - 4];
    else if constexpr (I < 12) return c[I - 8];
    else                       return d[I - 12];
}

// 8 taps x 8 outputs, all indices compile-time static.
// ASC=false (convolution): out j, tap kp uses W[8 + j - kp]  (range 1..15)
// ASC=true  (correlation): out j, tap kp uses W[j + kp]      (range 0..14)
template<bool ASC>
__device__ __forceinline__ void group8(const f32x4& w0, const f32x4& w1,
                                       const f32x4& w2, const f32x4& w3,
                                       float acc[8], const float* __restrict__ hh)
{
#define GIDX(j,kp) (ASC ? ((j)+(kp)) : (8+(j)-(kp)))
#define GTAP(kp) { const float hk = hh[kp]; \
    acc[0]=fmaf(hk, wselT<GIDX(0,kp)>(w0,w1,w2,w3), acc[0]); \
    acc[1]=fmaf(hk, wselT<GIDX(1,kp)>(w0,w1,w2,w3), acc[1]); \
    acc[2]=fmaf(hk, wselT<GIDX(2,kp)>(w0,w1,w2,w3), acc[2]); \
    acc[3]=fmaf(hk, wselT<GIDX(3,kp)>(w0,w1,w2,w3), acc[3]); \
    acc[4]=fmaf(hk, wselT<GIDX(4,kp)>(w0,w1,w2,w3), acc[4]); \
    acc[5]=fmaf(hk, wselT<GIDX(5,kp)>(w0,w1,w2,w3), acc[5]); \
    acc[6]=fmaf(hk, wselT<GIDX(6,kp)>(w0,w1,w2,w3), acc[6]); \
    acc[7]=fmaf(hk, wselT<GIDX(7,kp)>(w0,w1,w2,w3), acc[7]); }
    GTAP(0) GTAP(1) GTAP(2) GTAP(3) GTAP(4) GTAP(5) GTAP(6) GTAP(7)
#undef GTAP
#undef GIDX
}

// ---------------------------------------------------------------------------
// Causal FIR (convolution): y[n] = sum_k h[k] x[n-k], taps zero-padded to Lpad.
// One block = (channel, 2048-output tile); thread t owns outputs n0+8t..+7.
// Window base u0 = 8t + Lpad + 4 has u0%8==4 -> half-offsets (+0,+8,+12,+20).
// DELAYED: x fetched as (p+d<N ? in[p+d] : 0) at staging (exact ref semantics).
// ---------------------------------------------------------------------------
template<int Lpad, bool ABSIN, bool DELAYED>
__global__ __launch_bounds__(BLOCK)
void fir_fast(const float* __restrict__ in, long instride,
              const float* __restrict__ taps, int tapstride,
              float* __restrict__ out, long ostride,
              const int* __restrict__ delays, int chan0)
{
    extern __shared__ float s[];
    const int c  = blockIdx.y;
    const int n0 = blockIdx.x * TILE;
    const float* __restrict__ xin = in + (long)c * instride;
    const float* __restrict__ hC  = taps + (long)c * tapstride;
    float* __restrict__ y         = out + (long)c * ostride;
    int d = 0;
    if (DELAYED) d = delays[chan0 + c];

    constexpr int PADLO = 13;
    constexpr int E = TILE + Lpad - 1;
    for (int i = threadIdx.x; i < E; i += BLOCK) {
        int p = n0 - (Lpad - 1) + i;
        float v = 0.f;
        if (p >= 0 && p < NSAMP) {
            int q = p + d;
            if (!DELAYED || q < NSAMP) v = xin[q];
        }
        if (ABSIN) v = fabsf(v);
        s[physu(i + PADLO)] = v;
    }
    __syncthreads();

    const int t = threadIdx.x;
    const int ubase = 8 * t + (Lpad - 1) + PADLO;  // u-index of x[n0+8t]
    const int u0 = ubase - 8;                      // W[0] of group 0 (u0%8==4)
    const int A0 = physu(u0);

    float acc[8] = {0.f,0.f,0.f,0.f,0.f,0.f,0.f,0.f};
    f32x4 p0a = *(const f32x4*)(s + A0);
    f32x4 p0b = *(const f32x4*)(s + A0 + 8);
    f32x4 p1a = *(const f32x4*)(s + A0 + 12);
    f32x4 p1b = *(const f32x4*)(s + A0 + 20);
    f32x4 p2a, p2b;

    int idx = A0 - 36;
    const float* __restrict__ hh = hC;
    constexpr int NIT = Lpad / 24;
#pragma unroll 1
    for (int it = 0; it < NIT; ++it) {
        // g=3it: LO=P0 HI=P1, load next LO -> P2 (base A0-12(3it+1) = idx+24)
        p2a = *(const f32x4*)(s + idx + 24);
        p2b = *(const f32x4*)(s + idx + 32);
        group8<false>(p0a, p0b, p1a, p1b, acc, hh);
        // g=3it+1: LO=P2 HI=P0, load -> P1 (base idx+12)
        p1a = *(const f32x4*)(s + idx + 12);
        p1b = *(const f32x4*)(s + idx + 20);
        group8<false>(p2a, p2b, p0a, p0b, acc, hh + 8);
        // g=3it+2: LO=P1 HI=P2, load -> P0 (base idx)
        p0a = *(const f32x4*)(s + idx);
        p0b = *(const f32x4*)(s + idx + 8);
        group8<false>(p1a, p1b, p2a, p2b, acc, hh + 16);
        idx -= 36;
        hh  += 24;
    }

    const int nb = n0 + 8 * t;
#pragma unroll
    for (int j = 0; j < 8; j++)
        if (nb + j < NSAMP) y[nb + j] = acc[j];
}

// ---------------------------------------------------------------------------
// Anti-causal envelope FIR fused with recruitment gain:
// env[n] = sum_k h[k] |envf[n+k]| (zero past N-1), then pc *= gain(env).
// Window base u0g = 8t+8g has u0%8==0 -> logical 8-block is physically
// CONTIGUOUS [A0+12g, A0+12g+8): half-offsets (+0,+4) / (+12,+16).
// (Round-2 bug: used descending offsets (+8,+20) -> read the pad region.)
// ---------------------------------------------------------------------------
template<int Lpad>
__global__ __launch_bounds__(BLOCK)
void env_gain_fast(const float* __restrict__ envf,
                   const float* __restrict__ taps, int tapstride,
                   float* __restrict__ pc,
                   const float* __restrict__ ratios,
                   const float* __restrict__ eqloud)
{
    extern __shared__ float s[];
    const int c  = blockIdx.y;
    const int n0 = blockIdx.x * TILE;
    const float* __restrict__ xin = envf + (long)c * NSAMP;
    const float* __restrict__ hC  = taps + (long)c * tapstride;

    constexpr int E2 = TILE + Lpad + 16;
    for (int i = threadIdx.x; i < E2; i += BLOCK) {
        int p = n0 + i;
        float v = (p < NSAMP) ? fabsf(xin[p]) : 0.f;
        s[physu(i)] = v;
    }
    __syncthreads();

    const int t = threadIdx.x;
    const int A0 = 12 * t;                 // physu(8t), block 0 of this thread

    float acc[8] = {0.f,0.f,0.f,0.f,0.f,0.f,0.f,0.f};
    f32x4 p0a = *(const f32x4*)(s + A0);        // W[0..3]  (block 0)
    f32x4 p0b = *(const f32x4*)(s + A0 + 4);    // W[4..7]
    f32x4 p1a = *(const f32x4*)(s + A0 + 12);   // W[8..11] (block 1)
    f32x4 p1b = *(const f32x4*)(s + A0 + 16);   // W[12..15]
    f32x4 p2a, p2b;

    int idx = A0 + 24;                     // physical base of block 3it+2
    const float* __restrict__ hh = hC;
    constexpr int NIT = Lpad / 24;
#pragma unroll 1
    for (int it = 0; it < NIT; ++it) {
        // g=3it: LO=P0 HI=P1, prefetch block g+2 -> P2
        p2a = *(const f32x4*)(s + idx);
        p2b = *(const f32x4*)(s + idx + 4);
        group8<true>(p0a, p0b, p1a, p1b, acc, hh);
        // g=3it+1: LO=P1 HI=P2, prefetch block g+2 -> P0
        p0a = *(const f32x4*)(s + idx + 12);
        p0b = *(const f32x4*)(s + idx + 16);
        group8<true>(p1a, p1b, p2a, p2b, acc, hh + 8);
        // g=3it+2: LO=P2 HI=P0, prefetch -> P1
        p1a = *(const f32x4*)(s + idx + 24);
        p1b = *(const f32x4*)(s + idx + 28);
        group8<true>(p2a, p2b, p0a, p0b, acc, hh + 16);
        idx += 36;
        hh  += 24;
    }

    const float emax = exp10f(0.05f * (eqloud[c] - 100.0f));
    const float er   = fmaxf(ratios[c], -5.0f) - 1.0f;
    const int nb = n0 + 8 * t;
#pragma unroll
    for (int j = 0; j < 8; j++) {
        int n = nb + j;
        if (n < NSAMP) {
            float env = acc[j];
            float ecl = fminf(fmaxf(env, 1e-9f), emax);
            float enr = fmaxf(ecl / emax, 1e-6f);
            float g   = fminf(powf(enr, er), 100.0f);
            long id = (long)c * NSAMP + n;
            pc[id] = pc[id] * g;
        }
    }
}

// out[c,m] = sum_k a[c,k] a[c,m-k]; writes zeros for m in [Mlen, Mpad)
__global__ void conv_self(const float* __restrict__ a, int astride, int La,
                          float* __restrict__ out, int ostride, int Mlen, int Mpad)
{
    extern __shared__ float s[];
    const int c = blockIdx.y;
    const float* __restrict__ ar = a + (long)c * astride;
    for (int i = threadIdx.x; i < La; i += blockDim.x) s[i] = ar[i];
    __syncthreads();
    int m = blockIdx.x * blockDim.x + threadIdx.x;
    float acc = 0.f;
    for (int k = 0; k < La; k++) {
        int mi = m - k;
        float bv = ((unsigned)mi < (unsigned)La) ? s[mi] : 0.f;
        acc = fmaf(s[k], bv, acc);
    }
    if (m < Mpad) out[(long)c * ostride + m] = (m < Mlen) ? acc : 0.f;
}

// dst[c, 0..Lpad) = k<L ? src[c,k] : 0
__global__ void pad_copy(const float* __restrict__ src, int L, int sstride,
                         float* __restrict__ dst, int Lpad)
{
    int c = blockIdx.y;
    int k = blockIdx.x * blockDim.x + threadIdx.x;
    if (k < Lpad) dst[(long)c * Lpad + k] = (k < L) ? src[(long)c * sstride + k] : 0.f;
}

// pass_del for channels 0..3: b[c,n] = (n+d<N) ? a[c,n+d] : 0
__global__ void delay_copy(const float* __restrict__ a, float* __restrict__ b,
                           const int* __restrict__ delays)
{
    int c = blockIdx.y;
    int n = blockIdx.x * blockDim.x + threadIdx.x;
    if (n < NSAMP) {
        int q = n + delays[c];
        b[(long)c * NSAMP + n] = (q < NSAMP) ? a[(long)c * NSAMP + q] : 0.f;
    }
}

// coch[n] = 10^-0.5 * sum_c coch_c[c,n]
__global__ void reduce_coch(const float* __restrict__ b, float* __restrict__ coch)
{
    int n = blockIdx.x * blockDim.x + threadIdx.x;
    if (n < NSAMP) {
        float sum = 0.f;
        for (int c = 0; c < NCH; c++) sum += b[(long)c * NSAMP + n];
        coch[n] = sum * 0.31622776601683794f;
    }
}

static inline size_t lds_bytes_umax(int umax)
{
    return (size_t)(umax + ((umax >> 3) << 2) + 8) * 4;
}
static inline size_t lds_desc(int Lpad) { return lds_bytes_umax(TILE + Lpad - 2 + 13); }
static inline size_t lds_asc(int Lpad)  { return lds_bytes_umax(TILE + Lpad + 15); }

extern "C" void kernel_launch(void* const* d_in, const int* in_sizes, int n_in,
                              void* d_out, int out_size, void* d_ws, size_t ws_size,
                              hipStream_t stream)
{
    const float* x       = (const float*)d_in[0];
    const float* src_fwd = (const float*)d_in[1];
    const float* src_bwd = (const float*)d_in[2];
    const float* lpf     = (const float*)d_in[3];
    const float* gtn     = (const float*)d_in[4];  // [28,1000]
    const float* hp      = (const float*)d_in[5];  // [24,1000]
    const float* clpf    = (const float*)d_in[6];  // [28,2000]
    const float* ratios  = (const float*)d_in[7];
    const float* eqloud  = (const float*)d_in[8];
    const int*   delays  = (const int*)d_in[9];
    float* out = (float*)d_out;

    float* ws   = (float*)d_ws;
    const size_t CNs = (size_t)NCH * NSAMP;
    float* bufA  = ws;                         // C*N  (y4, then env_f)
    float* bufB  = bufA + CNs;                 // C*N  (pass_del -> coch_c)
    float* xc    = bufB + CNs;                 // N
    float* coch  = xc + NSAMP;                 // N
    float* t1    = coch + NSAMP;               // N
    float* h2    = t1 + NSAMP;                 // 28*2000
    float* h4    = h2 + (size_t)NCH * 2000;    // 28*LP_GT4
    float* hpP   = h4 + (size_t)NCH * LP_GT4;  // 24*LP_HP
    float* clpfP = hpP + (size_t)HPCH * LP_HP; // 28*LP_ENV
    float* sfP   = clpfP + (size_t)NCH * LP_ENV; // LP_SRC
    float* sbP   = sfP + LP_SRC;               // LP_SRC
    float* lpP   = sbP + LP_SRC;               // LP_LPF

    dim3 blk(BLOCK);
    const int NT = (NSAMP + TILE - 1) / TILE;  // 108

    // --- filter prep ---
    // h2 = gtn*gtn (len 1999); h4 = h2*h2 (len 3997, zero-padded to 4008)
    conv_self<<<dim3((1999 + BLOCK - 1) / BLOCK, NCH), blk, L_GT * 4, stream>>>(
        gtn, L_GT, L_GT, h2, 2000, 1999, 1999);
    conv_self<<<dim3((LP_GT4 + BLOCK - 1) / BLOCK, NCH), blk, 1999 * 4, stream>>>(
        h2, 2000, 1999, h4, LP_GT4, L4, LP_GT4);
    pad_copy<<<dim3((LP_HP + BLOCK - 1) / BLOCK, HPCH), blk, 0, stream>>>(
        hp, L_GT, L_GT, hpP, LP_HP);
    pad_copy<<<dim3((LP_ENV + BLOCK - 1) / BLOCK, NCH), blk, 0, stream>>>(
        clpf, L_ENV, L_ENV, clpfP, LP_ENV);
    pad_copy<<<dim3(2, 1), dim3(256), 0, stream>>>(src_fwd, 256, 256, sfP, LP_SRC);
    pad_copy<<<dim3(2, 1), dim3(256), 0, stream>>>(src_bwd, 256, 256, sbP, LP_SRC);
    pad_copy<<<dim3(1, 1), dim3(256), 0, stream>>>(lpf, 133, 133, lpP, LP_LPF);

    // --- signal path ---
    // xc = fir1(x, src_fwd)
    fir_fast<LP_SRC, false, false><<<dim3(NT, 1), blk, lds_desc(LP_SRC), stream>>>(
        x, 0, sfP, 0, xc, 0, nullptr, 0);

    // y4[c] = xc * h4[c]  (4-pass gammatone collapsed)
    fir_fast<LP_GT4, false, false><<<dim3(NT, NCH), blk, lds_desc(LP_GT4), stream>>>(
        xc, 0, h4, LP_GT4, bufA, NSAMP, nullptr, 0);

    // pass_del ch 0..3: delayed copy
    delay_copy<<<dim3((NSAMP + BLOCK - 1) / BLOCK, 4), blk, 0, stream>>>(bufA, bufB, delays);

    // pass_del ch 4..27: HP FIR with delay at input fetch
    fir_fast<LP_HP, false, true><<<dim3(NT, HPCH), blk, lds_desc(LP_HP), stream>>>(
        bufA + 4 * (size_t)NSAMP, NSAMP, hpP, LP_HP,
        bufB + 4 * (size_t)NSAMP, NSAMP, delays, 4);

    // env_f = fir(|pass_del|, chan_lpf)
    fir_fast<LP_ENV, true, false><<<dim3(NT, NCH), blk, lds_desc(LP_ENV), stream>>>(
        bufB, NSAMP, clpfP, LP_ENV, bufA, NSAMP, nullptr, 0);

    // env (anti-causal) + recruitment gain
    env_gain_fast<LP_ENV><<<dim3(NT, NCH), blk, lds_asc(LP_ENV), stream>>>(
        bufA, clpfP, LP_ENV, bufB, ratios, eqloud);

    // coch = 10^-0.5 * sum_c coch_c
    reduce_coch<<<dim3((NSAMP + BLOCK - 1) / BLOCK), blk, 0, stream>>>(bufB, coch);

    // out = fir1(fir1(coch, src_bwd), lpf)
    fir_fast<LP_SRC, false, false><<<dim3(NT, 1), blk, lds_desc(LP_SRC), stream>>>(
        coch, 0, sbP, 0, t1, 0, nullptr, 0);
    fir_fast<LP_LPF, false, false><<<dim3(NT, 1), blk, lds_desc(LP_LPF), stream>>>(
        t1, 0, lpP, 0, out, 0, nullptr, 0);
}

// Round 4
// 1533.941 us; speedup vs baseline: 1.4768x; 1.1733x over previous
//
#include <hip/hip_runtime.h>
#include <math.h>

// Problem constants (match reference)
#define NSAMP 220500
#define NCH   28
#define L_GT  1000
#define L_ENV 2000
#define L4    3997   // 4x cascaded gammatone -> combined FIR length
#define HPCH  24     // channels 4..27 get HP
#define TILE  2048
#define BLOCK 256

// Padded tap lengths (multiples of 24 -> tapcount/8 divisible by 3, no tail)
#define LP_GT4 4008
#define LP_HP  1008
#define LP_ENV 2016
#define LP_SRC 264
#define LP_LPF 144

// Stride-9 LDS layout: logical float u -> physical u + (u>>3): each aligned
// 8-float block b occupies phys [9b, 9b+8). Per-lane block-base stride = 9
// dwords (odd) -> any dword-phase bank pattern is <=2-way (free, m136).
// (Round-3 lesson: b128 at 12-dword lane stride = gcd(12,32)=4 -> 8-way
// conflict, +24 cyc/read measured. Odd b32 strides are the proven-clean path.)
__device__ __forceinline__ int phys9(int u) { return u + (u >> 3); }

// 8 taps x 8 outputs, all indices compile-time static.
// ASC=false (convolution): out j, tap kp uses W[8 + j - kp]  (range 1..15; W[0] dead)
// ASC=true  (correlation): out j, tap kp uses W[j + kp]      (range 0..14; W[15] dead)
template<bool ASC>
__device__ __forceinline__ void group8(const float (&LO)[8], const float (&HI)[8],
                                       float (&acc)[8], const float* __restrict__ hh)
{
#define GIDX(j,kp) (ASC ? ((j)+(kp)) : (8+(j)-(kp)))
#define WSEL(m) ((m) < 8 ? LO[(m) & 7] : HI[(m) & 7])
#define GTAP(kp) { const float hk = hh[kp]; \
    acc[0]=fmaf(hk, WSEL(GIDX(0,kp)), acc[0]); \
    acc[1]=fmaf(hk, WSEL(GIDX(1,kp)), acc[1]); \
    acc[2]=fmaf(hk, WSEL(GIDX(2,kp)), acc[2]); \
    acc[3]=fmaf(hk, WSEL(GIDX(3,kp)), acc[3]); \
    acc[4]=fmaf(hk, WSEL(GIDX(4,kp)), acc[4]); \
    acc[5]=fmaf(hk, WSEL(GIDX(5,kp)), acc[5]); \
    acc[6]=fmaf(hk, WSEL(GIDX(6,kp)), acc[6]); \
    acc[7]=fmaf(hk, WSEL(GIDX(7,kp)), acc[7]); }
    GTAP(0) GTAP(1) GTAP(2) GTAP(3) GTAP(4) GTAP(5) GTAP(6) GTAP(7)
#undef GTAP
#undef WSEL
#undef GIDX
}

// ---------------------------------------------------------------------------
// Causal FIR (convolution): y[n] = sum_k h[k] x[n-k], taps zero-padded to Lpad.
// One block = (channel, 2048-output tile); thread t owns outputs n0+8t..+7.
// W[m] of group kb lives at u' = (8t + Lpad - kb) + m; each new 8-block is
// phys-consecutive [9q,9q+8) with lane stride 9 dwords. PADLO=9.
// DELAYED: x fetched as (p+d<N ? in[p+d] : 0) at staging (exact ref semantics).
// ---------------------------------------------------------------------------
template<int Lpad, bool ABSIN, bool DELAYED>
__global__ __launch_bounds__(BLOCK)
void fir_fast(const float* __restrict__ in, long instride,
              const float* __restrict__ taps, int tapstride,
              float* __restrict__ out, long ostride,
              const int* __restrict__ delays, int chan0)
{
    extern __shared__ float s[];
    const int c  = blockIdx.y;
    const int n0 = blockIdx.x * TILE;
    const float* __restrict__ xin = in + (long)c * instride;
    const float* __restrict__ hC  = taps + (long)c * tapstride;
    float* __restrict__ y         = out + (long)c * ostride;
    int d = 0;
    if (DELAYED) d = delays[chan0 + c];

    constexpr int E = TILE + Lpad - 1;   // staged logical extent, u' = i + 9
    for (int i = threadIdx.x; i < E; i += BLOCK) {
        int p = n0 - (Lpad - 1) + i;
        float v = 0.f;
        if (p >= 0 && p < NSAMP) {
            int q = p + d;
            if (!DELAYED || q < NSAMP) v = xin[q];
        }
        if (ABSIN) v = fabsf(v);
        s[phys9(i + 9)] = v;
    }
    __syncthreads();

    const int t = threadIdx.x;
    const int B = 9 * (t + Lpad / 8);    // phys base of block q0 (W[0..7], kb=0)

    float Ab[8], Bb[8], Cb[8];
    float acc[8] = {0.f,0.f,0.f,0.f,0.f,0.f,0.f,0.f};
#pragma unroll
    for (int m = 0; m < 8; m++) Ab[m] = s[B + m];        // block q0
#pragma unroll
    for (int m = 0; m < 8; m++) Bb[m] = s[B + 9 + m];    // block q0+1

    int idx = B - 27;
    const float* __restrict__ hh = hC;
    constexpr int NIT = Lpad / 24;
#pragma unroll 1
    for (int it = 0; it < NIT; ++it) {
        const float* p = s + idx;
        // kb=24it: LO=Ab(q0-3it) HI=Bb(q0-3it+1); prefetch Cb <- q0-3it-1
#pragma unroll
        for (int m = 0; m < 8; m++) Cb[m] = p[18 + m];
        group8<false>(Ab, Bb, acc, hh);
        // kb=24it+8: LO=Cb HI=Ab; prefetch Bb <- q0-3it-2
#pragma unroll
        for (int m = 0; m < 8; m++) Bb[m] = p[9 + m];
        group8<false>(Cb, Ab, acc, hh + 8);
        // kb=24it+16: LO=Bb HI=Cb; prefetch Ab <- q0-3it-3
#pragma unroll
        for (int m = 0; m < 8; m++) Ab[m] = p[m];
        group8<false>(Bb, Cb, acc, hh + 16);
        idx -= 27;
        hh  += 24;
    }

    const int nb = n0 + 8 * t;
#pragma unroll
    for (int j = 0; j < 8; j++)
        if (nb + j < NSAMP) y[nb + j] = acc[j];
}

// ---------------------------------------------------------------------------
// Anti-causal envelope FIR fused with recruitment gain:
// env[n] = sum_k h[k] |envf[n+k]| (zero past N-1), then pc *= gain(env).
// W[m] of group g lives at u' = 8(t+g) + m; PADLO=0; lane stride 9 dwords.
// ---------------------------------------------------------------------------
template<int Lpad>
__global__ __launch_bounds__(BLOCK)
void env_gain_fast(const float* __restrict__ envf,
                   const float* __restrict__ taps, int tapstride,
                   float* __restrict__ pc,
                   const float* __restrict__ ratios,
                   const float* __restrict__ eqloud)
{
    extern __shared__ float s[];
    const int c  = blockIdx.y;
    const int n0 = blockIdx.x * TILE;
    const float* __restrict__ xin = envf + (long)c * NSAMP;
    const float* __restrict__ hC  = taps + (long)c * tapstride;

    constexpr int E2 = TILE + Lpad + 8;  // covers all reads incl. last prefetch
    for (int i = threadIdx.x; i < E2; i += BLOCK) {
        int p = n0 + i;
        float v = (p < NSAMP) ? fabsf(xin[p]) : 0.f;
        s[phys9(i)] = v;
    }
    __syncthreads();

    const int t = threadIdx.x;
    float Ab[8], Bb[8], Cb[8];
    float acc[8] = {0.f,0.f,0.f,0.f,0.f,0.f,0.f,0.f};
#pragma unroll
    for (int m = 0; m < 8; m++) Ab[m] = s[9 * t + m];        // block t
#pragma unroll
    for (int m = 0; m < 8; m++) Bb[m] = s[9 * t + 9 + m];    // block t+1

    int idx = 9 * t;
    const float* __restrict__ hh = hC;
    constexpr int NIT = Lpad / 24;
#pragma unroll 1
    for (int it = 0; it < NIT; ++it) {
        const float* p = s + idx;
        // g=3it: LO=Ab(t+3it) HI=Bb(t+3it+1); prefetch Cb <- t+3it+2
#pragma unroll
        for (int m = 0; m < 8; m++) Cb[m] = p[18 + m];
        group8<true>(Ab, Bb, acc, hh);
        // g=3it+1: LO=Bb HI=Cb; prefetch Ab <- t+3it+3
#pragma unroll
        for (int m = 0; m < 8; m++) Ab[m] = p[27 + m];
        group8<true>(Bb, Cb, acc, hh + 8);
        // g=3it+2: LO=Cb HI=Ab; prefetch Bb <- t+3it+4
#pragma unroll
        for (int m = 0; m < 8; m++) Bb[m] = p[36 + m];
        group8<true>(Cb, Ab, acc, hh + 16);
        idx += 27;
        hh  += 24;
    }

    const float emax = exp10f(0.05f * (eqloud[c] - 100.0f));
    const float er   = fmaxf(ratios[c], -5.0f) - 1.0f;
    const int nb = n0 + 8 * t;
#pragma unroll
    for (int j = 0; j < 8; j++) {
        int n = nb + j;
        if (n < NSAMP) {
            float env = acc[j];
            float ecl = fminf(fmaxf(env, 1e-9f), emax);
            float enr = fmaxf(ecl / emax, 1e-6f);
            float g   = fminf(powf(enr, er), 100.0f);
            long id = (long)c * NSAMP + n;
            pc[id] = pc[id] * g;
        }
    }
}

// out[c,m] = sum_k a[c,k] a[c,m-k]; writes zeros for m in [Mlen, Mpad)
__global__ void conv_self(const float* __restrict__ a, int astride, int La,
                          float* __restrict__ out, int ostride, int Mlen, int Mpad)
{
    extern __shared__ float s[];
    const int c = blockIdx.y;
    const float* __restrict__ ar = a + (long)c * astride;
    for (int i = threadIdx.x; i < La; i += blockDim.x) s[i] = ar[i];
    __syncthreads();
    int m = blockIdx.x * blockDim.x + threadIdx.x;
    float acc = 0.f;
    for (int k = 0; k < La; k++) {
        int mi = m - k;
        float bv = ((unsigned)mi < (unsigned)La) ? s[mi] : 0.f;
        acc = fmaf(s[k], bv, acc);
    }
    if (m < Mpad) out[(long)c * ostride + m] = (m < Mlen) ? acc : 0.f;
}

// dst[c, 0..Lpad) = k<L ? src[c,k] : 0
__global__ void pad_copy(const float* __restrict__ src, int L, int sstride,
                         float* __restrict__ dst, int Lpad)
{
    int c = blockIdx.y;
    int k = blockIdx.x * blockDim.x + threadIdx.x;
    if (k < Lpad) dst[(long)c * Lpad + k] = (k < L) ? src[(long)c * sstride + k] : 0.f;
}

// pass_del for channels 0..3: b[c,n] = (n+d<N) ? a[c,n+d] : 0
__global__ void delay_copy(const float* __restrict__ a, float* __restrict__ b,
                           const int* __restrict__ delays)
{
    int c = blockIdx.y;
    int n = blockIdx.x * blockDim.x + threadIdx.x;
    if (n < NSAMP) {
        int q = n + delays[c];
        b[(long)c * NSAMP + n] = (q < NSAMP) ? a[(long)c * NSAMP + q] : 0.f;
    }
}

// coch[n] = 10^-0.5 * sum_c coch_c[c,n]
__global__ void reduce_coch(const float* __restrict__ b, float* __restrict__ coch)
{
    int n = blockIdx.x * blockDim.x + threadIdx.x;
    if (n < NSAMP) {
        float sum = 0.f;
        for (int c = 0; c < NCH; c++) sum += b[(long)c * NSAMP + n];
        coch[n] = sum * 0.31622776601683794f;
    }
}

// LDS bytes for max logical index u'max = TILE + Lpad + 7 (both variants)
static inline size_t lds9(int Lpad)
{
    int umax = TILE + Lpad + 7;
    return (size_t)(umax + (umax >> 3) + 16) * 4;
}

extern "C" void kernel_launch(void* const* d_in, const int* in_sizes, int n_in,
                              void* d_out, int out_size, void* d_ws, size_t ws_size,
                              hipStream_t stream)
{
    const float* x       = (const float*)d_in[0];
    const float* src_fwd = (const float*)d_in[1];
    const float* src_bwd = (const float*)d_in[2];
    const float* lpf     = (const float*)d_in[3];
    const float* gtn     = (const float*)d_in[4];  // [28,1000]
    const float* hp      = (const float*)d_in[5];  // [24,1000]
    const float* clpf    = (const float*)d_in[6];  // [28,2000]
    const float* ratios  = (const float*)d_in[7];
    const float* eqloud  = (const float*)d_in[8];
    const int*   delays  = (const int*)d_in[9];
    float* out = (float*)d_out;

    float* ws   = (float*)d_ws;
    const size_t CNs = (size_t)NCH * NSAMP;
    float* bufA  = ws;                         // C*N  (y4, then env_f)
    float* bufB  = bufA + CNs;                 // C*N  (pass_del -> coch_c)
    float* xc    = bufB + CNs;                 // N
    float* coch  = xc + NSAMP;                 // N
    float* t1    = coch + NSAMP;               // N
    float* h2    = t1 + NSAMP;                 // 28*2000
    float* h4    = h2 + (size_t)NCH * 2000;    // 28*LP_GT4
    float* hpP   = h4 + (size_t)NCH * LP_GT4;  // 24*LP_HP
    float* clpfP = hpP + (size_t)HPCH * LP_HP; // 28*LP_ENV
    float* sfP   = clpfP + (size_t)NCH * LP_ENV; // LP_SRC
    float* sbP   = sfP + LP_SRC;               // LP_SRC
    float* lpP   = sbP + LP_SRC;               // LP_LPF

    dim3 blk(BLOCK);
    const int NT = (NSAMP + TILE - 1) / TILE;  // 108

    // --- filter prep ---
    // h2 = gtn*gtn (len 1999); h4 = h2*h2 (len 3997, zero-padded to 4008)
    conv_self<<<dim3((1999 + BLOCK - 1) / BLOCK, NCH), blk, L_GT * 4, stream>>>(
        gtn, L_GT, L_GT, h2, 2000, 1999, 1999);
    conv_self<<<dim3((LP_GT4 + BLOCK - 1) / BLOCK, NCH), blk, 1999 * 4, stream>>>(
        h2, 2000, 1999, h4, LP_GT4, L4, LP_GT4);
    pad_copy<<<dim3((LP_HP + BLOCK - 1) / BLOCK, HPCH), blk, 0, stream>>>(
        hp, L_GT, L_GT, hpP, LP_HP);
    pad_copy<<<dim3((LP_ENV + BLOCK - 1) / BLOCK, NCH), blk, 0, stream>>>(
        clpf, L_ENV, L_ENV, clpfP, LP_ENV);
    pad_copy<<<dim3(2, 1), dim3(256), 0, stream>>>(src_fwd, 256, 256, sfP, LP_SRC);
    pad_copy<<<dim3(2, 1), dim3(256), 0, stream>>>(src_bwd, 256, 256, sbP, LP_SRC);
    pad_copy<<<dim3(1, 1), dim3(256), 0, stream>>>(lpf, 133, 133, lpP, LP_LPF);

    // --- signal path ---
    // xc = fir1(x, src_fwd)
    fir_fast<LP_SRC, false, false><<<dim3(NT, 1), blk, lds9(LP_SRC), stream>>>(
        x, 0, sfP, 0, xc, 0, nullptr, 0);

    // y4[c] = xc * h4[c]  (4-pass gammatone collapsed)
    fir_fast<LP_GT4, false, false><<<dim3(NT, NCH), blk, lds9(LP_GT4), stream>>>(
        xc, 0, h4, LP_GT4, bufA, NSAMP, nullptr, 0);

    // pass_del ch 0..3: delayed copy
    delay_copy<<<dim3((NSAMP + BLOCK - 1) / BLOCK, 4), blk, 0, stream>>>(bufA, bufB, delays);

    // pass_del ch 4..27: HP FIR with delay at input fetch
    fir_fast<LP_HP, false, true><<<dim3(NT, HPCH), blk, lds9(LP_HP), stream>>>(
        bufA + 4 * (size_t)NSAMP, NSAMP, hpP, LP_HP,
        bufB + 4 * (size_t)NSAMP, NSAMP, delays, 4);

    // env_f = fir(|pass_del|, chan_lpf)
    fir_fast<LP_ENV, true, false><<<dim3(NT, NCH), blk, lds9(LP_ENV), stream>>>(
        bufB, NSAMP, clpfP, LP_ENV, bufA, NSAMP, nullptr, 0);

    // env (anti-causal) + recruitment gain
    env_gain_fast<LP_ENV><<<dim3(NT, NCH), blk, lds9(LP_ENV), stream>>>(
        bufA, clpfP, LP_ENV, bufB, ratios, eqloud);

    // coch = 10^-0.5 * sum_c coch_c
    reduce_coch<<<dim3((NSAMP + BLOCK - 1) / BLOCK), blk, 0, stream>>>(bufB, coch);

    // out = fir1(fir1(coch, src_bwd), lpf)
    fir_fast<LP_SRC, false, false><<<dim3(NT, 1), blk, lds9(LP_SRC), stream>>>(
        coch, 0, sbP, 0, t1, 0, nullptr, 0);
    fir_fast<LP_LPF, false, false><<<dim3(NT, 1), blk, lds9(LP_LPF), stream>>>(
        t1, 0, lpP, 0, out, 0, nullptr, 0);
}